// Round 1
// baseline (443.140 us; speedup 1.0000x reference)
//
#include <hip/hip_runtime.h>
#include <hip/hip_bf16.h>

// ---------------------------------------------------------------------------
// GAT layer 0 only: reference returns outputs[-2] == elu(GATConv0(x)).
// Pipeline: gemm_h -> asad -> (count, scan, fill CSR by dst) -> aggregate.
// ---------------------------------------------------------------------------

#define NFEAT 256   // HEADS*HID == D_IN == 256
#define NHEADS 8
#define TE 128      // alpha tile (edges) staged in LDS

// h = x @ W0^T  : x [N,256], W0 [256,256] row-major (row c = out-channel c)
__global__ __launch_bounds__(256) void gemm_h(const float* __restrict__ x,
                                              const float* __restrict__ W,
                                              float* __restrict__ h, int N) {
    __shared__ float xs[64][65];
    __shared__ float ws[64][65];
    int tx = threadIdx.x & 15, ty = threadIdx.x >> 4;
    int brow = blockIdx.x * 64, bcol = blockIdx.y * 64;
    float acc[4][4] = {};
    for (int kc = 0; kc < 256; kc += 64) {
        for (int v = 0; v < 4; ++v) {
            int idx = threadIdx.x + v * 256;   // float4 slot 0..1023
            int r = idx >> 4;
            int kk = (idx & 15) * 4;
            int row = brow + r;
            float4 val = make_float4(0.f, 0.f, 0.f, 0.f);
            if (row < N) val = *(const float4*)(x + (size_t)row * NFEAT + kc + kk);
            xs[r][kk] = val.x; xs[r][kk + 1] = val.y; xs[r][kk + 2] = val.z; xs[r][kk + 3] = val.w;
            int c = bcol + r;  // always < 256
            float4 wv = *(const float4*)(W + (size_t)c * NFEAT + kc + kk);
            ws[r][kk] = wv.x; ws[r][kk + 1] = wv.y; ws[r][kk + 2] = wv.z; ws[r][kk + 3] = wv.w;
        }
        __syncthreads();
        for (int k = 0; k < 64; ++k) {
            float a[4], b[4];
#pragma unroll
            for (int i = 0; i < 4; ++i) a[i] = xs[ty * 4 + i][k];
#pragma unroll
            for (int j = 0; j < 4; ++j) b[j] = ws[tx * 4 + j][k];
#pragma unroll
            for (int i = 0; i < 4; ++i)
#pragma unroll
                for (int j = 0; j < 4; ++j) acc[i][j] += a[i] * b[j];
        }
        __syncthreads();
    }
#pragma unroll
    for (int i = 0; i < 4; ++i) {
        int row = brow + ty * 4 + i;
        if (row < N) {
#pragma unroll
            for (int j = 0; j < 4; ++j)
                h[(size_t)row * NFEAT + bcol + tx * 4 + j] = acc[i][j];
        }
    }
}

// a_s[n][hd] = sum_f h[n][hd*32+f]*att_s[hd*32+f]; same for a_d.
__global__ __launch_bounds__(256) void asad_kernel(const float* __restrict__ h,
                                                   const float* __restrict__ att_s,
                                                   const float* __restrict__ att_d,
                                                   float* __restrict__ a_s,
                                                   float* __restrict__ a_d, int N) {
    int n = blockIdx.x, t = threadIdx.x;
    float hv = h[(size_t)n * NFEAT + t];
    float ps = hv * att_s[t];
    float pd = hv * att_d[t];
#pragma unroll
    for (int off = 16; off; off >>= 1) {
        ps += __shfl_xor(ps, off, 32);
        pd += __shfl_xor(pd, off, 32);
    }
    if ((t & 31) == 0) {
        int hd = t >> 5;
        a_s[n * NHEADS + hd] = ps;
        a_d[n * NHEADS + hd] = pd;
    }
}

__global__ void count_kernel(const int* __restrict__ ei, int* __restrict__ counts, int E) {
    int e = blockIdx.x * 256 + threadIdx.x;
    if (e < E) atomicAdd(&counts[ei[E + e]], 1);
}

// exclusive scan of counts[0..n) -> offsets[0..n], plus copy into cursor.
__global__ __launch_bounds__(1024) void scan_kernel(const int* __restrict__ counts,
                                                    int* __restrict__ offsets,
                                                    int* __restrict__ cursor, int n) {
    int t = threadIdx.x;
    __shared__ int waveTot[16];
    __shared__ int s_carry;
    if (t == 0) s_carry = 0;
    __syncthreads();
    for (int base = 0; base < n; base += 4096) {
        int idx = base + t * 4;
        int a = 0, b = 0, c = 0, d = 0;
        if (idx + 3 < n) {
            int4 v = *(const int4*)(counts + idx);
            a = v.x; b = v.y; c = v.z; d = v.w;
        } else {
            if (idx < n) a = counts[idx];
            if (idx + 1 < n) b = counts[idx + 1];
            if (idx + 2 < n) c = counts[idx + 2];
            if (idx + 3 < n) d = counts[idx + 3];
        }
        int s0 = a, s1 = s0 + b, s2 = s1 + c, s3 = s2 + d;
        int lane = t & 63, wid = t >> 6;
        int incl = s3;
#pragma unroll
        for (int off = 1; off < 64; off <<= 1) {
            int u = __shfl_up(incl, off, 64);
            if (lane >= off) incl += u;
        }
        if (lane == 63) waveTot[wid] = incl;
        __syncthreads();
        int wpre = 0;
        for (int w = 0; w < wid; ++w) wpre += waveTot[w];
        int pre = s_carry + wpre + incl - s3;  // exclusive prefix for this thread's 1st elem
        if (idx < n)     { offsets[idx] = pre;          cursor[idx] = pre; }
        if (idx + 1 < n) { offsets[idx + 1] = pre + s0; cursor[idx + 1] = pre + s0; }
        if (idx + 2 < n) { offsets[idx + 2] = pre + s1; cursor[idx + 2] = pre + s1; }
        if (idx + 3 < n) { offsets[idx + 3] = pre + s2; cursor[idx + 3] = pre + s2; }
        __syncthreads();
        if (t == 1023) s_carry = s_carry + wpre + incl;
        __syncthreads();
    }
    if (t == 0) offsets[n] = s_carry;
}

__global__ void fill_kernel(const int* __restrict__ ei, int* __restrict__ cursor,
                            int* __restrict__ csr_src, int E) {
    int e = blockIdx.x * 256 + threadIdx.x;
    if (e < E) {
        int d = ei[E + e];
        int pos = atomicAdd(&cursor[d], 1);
        csr_src[pos] = ei[e];
    }
}

__device__ __forceinline__ float leaky02(float x) { return x >= 0.f ? x : 0.2f * x; }

// One block (256 thr) per destination node: softmax over incoming edges
// (+ self loop), then gather-aggregate alpha*h[src], then ELU(+bias).
__global__ __launch_bounds__(256) void aggregate_kernel(
    const float* __restrict__ h, const float* __restrict__ a_s,
    const float* __restrict__ a_d, const int* __restrict__ offsets,
    const int* __restrict__ csr_src, const float* __restrict__ b0,
    float* __restrict__ out, int N) {
    int n = blockIdx.x;
    int t = threadIdx.x;
    int start = offsets[n];
    int deg = offsets[n + 1] - start;
    int tdeg = deg + 1;  // virtual self loop at index == deg

    __shared__ float s_m[NHEADS], s_inv[NHEADS];
    __shared__ float s_alpha[TE][NHEADS];
    __shared__ int s_src[TE];
    __shared__ float s_part[4][NFEAT];

    int g = t >> 5, gl = t & 31;
    float ad = a_d[n * NHEADS + g];

    // phase 1: per-head max then denom (streaming, 32-lane groups)
    float mloc = -3.4e38f;
    for (int i = gl; i < tdeg; i += 32) {
        int s = (i < deg) ? csr_src[start + i] : n;
        float l = leaky02(a_s[s * NHEADS + g] + ad);
        mloc = fmaxf(mloc, l);
    }
#pragma unroll
    for (int off = 16; off; off >>= 1) mloc = fmaxf(mloc, __shfl_xor(mloc, off, 32));
    float dloc = 0.f;
    for (int i = gl; i < tdeg; i += 32) {
        int s = (i < deg) ? csr_src[start + i] : n;
        float l = leaky02(a_s[s * NHEADS + g] + ad);
        dloc += __expf(l - mloc);
    }
#pragma unroll
    for (int off = 16; off; off >>= 1) dloc += __shfl_xor(dloc, off, 32);
    if (gl == 0) {
        s_m[g] = mloc;
        s_inv[g] = 1.f / (dloc + 1e-16f);
    }
    __syncthreads();

    // phase 2: tiled alpha computation + float4 gather-accumulate
    int et = t >> 6;       // 4 edge-parallel groups
    int f4 = t & 63;       // feature quad [f4*4, f4*4+4)
    int hd4 = f4 >> 3;     // head of this quad
    float4 acc = make_float4(0.f, 0.f, 0.f, 0.f);
    for (int tb = 0; tb < tdeg; tb += TE) {
        int tn = min(TE, tdeg - tb);
        __syncthreads();  // protect s_alpha/s_src reuse
        for (int w = t; w < tn * NHEADS; w += 256) {
            int e = w >> 3, hd = w & 7;
            int i = tb + e;
            int s = (i < deg) ? csr_src[start + i] : n;
            if (hd == 0) s_src[e] = s;
            float l = leaky02(a_s[s * NHEADS + hd] + a_d[n * NHEADS + hd]);
            s_alpha[e][hd] = __expf(l - s_m[hd]) * s_inv[hd];
        }
        __syncthreads();
        for (int e = et; e < tn; e += 4) {
            int s = s_src[e];
            float al = s_alpha[e][hd4];
            float4 hv = *(const float4*)(h + (size_t)s * NFEAT + f4 * 4);
            acc.x += al * hv.x;
            acc.y += al * hv.y;
            acc.z += al * hv.z;
            acc.w += al * hv.w;
        }
    }
    s_part[et][f4 * 4 + 0] = acc.x;
    s_part[et][f4 * 4 + 1] = acc.y;
    s_part[et][f4 * 4 + 2] = acc.z;
    s_part[et][f4 * 4 + 3] = acc.w;
    __syncthreads();
    float tot = s_part[0][t] + s_part[1][t] + s_part[2][t] + s_part[3][t];
    tot += b0[t];
    out[(size_t)n * NFEAT + t] = tot > 0.f ? tot : (__expf(tot) - 1.f);
}

extern "C" void kernel_launch(void* const* d_in, const int* in_sizes, int n_in,
                              void* d_out, int out_size, void* d_ws, size_t ws_size,
                              hipStream_t stream) {
    const float* x     = (const float*)d_in[0];
    const int*   ei    = (const int*)d_in[1];
    const float* W0    = (const float*)d_in[2];
    const float* att_s = (const float*)d_in[3];
    const float* att_d = (const float*)d_in[4];
    const float* b0    = (const float*)d_in[5];
    float* out = (float*)d_out;

    int N = in_sizes[0] / NFEAT;  // 50000
    int E = in_sizes[1] / 2;      // 800000

    char* base = (char*)d_ws;
    size_t off = 0;
    auto nxt = [&](size_t bytes) -> void* {
        void* p = base + off;
        off = (off + bytes + 255) & ~(size_t)255;
        return p;
    };
    float* h       = (float*)nxt(sizeof(float) * (size_t)N * NFEAT);
    float* a_s     = (float*)nxt(sizeof(float) * (size_t)N * NHEADS);
    float* a_d     = (float*)nxt(sizeof(float) * (size_t)N * NHEADS);
    int*   counts  = (int*)nxt(sizeof(int) * N);
    int*   offsets = (int*)nxt(sizeof(int) * (N + 1));
    int*   cursor  = (int*)nxt(sizeof(int) * N);
    int*   csr     = (int*)nxt(sizeof(int) * E);

    hipMemsetAsync(counts, 0, sizeof(int) * N, stream);

    dim3 gg((N + 63) / 64, NFEAT / 64);
    gemm_h<<<gg, 256, 0, stream>>>(x, W0, h, N);
    asad_kernel<<<N, 256, 0, stream>>>(h, att_s, att_d, a_s, a_d, N);
    count_kernel<<<(E + 255) / 256, 256, 0, stream>>>(ei, counts, E);
    scan_kernel<<<1, 1024, 0, stream>>>(counts, offsets, cursor, N);
    fill_kernel<<<(E + 255) / 256, 256, 0, stream>>>(ei, cursor, csr, E);
    aggregate_kernel<<<N, 256, 0, stream>>>(h, a_s, a_d, offsets, csr, b0, out, N);
}

// Round 2
// 346.041 us; speedup vs baseline: 1.2806x; 1.2806x over previous
//
#include <hip/hip_runtime.h>
#include <hip/hip_bf16.h>

// ---------------------------------------------------------------------------
// GAT layer 0 only: reference returns outputs[-2] == elu(GATConv0(x)).
// Pipeline: gemm_h (bf16-MFMA, split precision) -> asad -> CSR -> aggregate.
// ---------------------------------------------------------------------------

#define NFEAT 256   // HEADS*HID == D_IN == 256
#define NHEADS 8
#define TE 128      // alpha tile (edges) staged in LDS

typedef __attribute__((ext_vector_type(8))) short short8v;
typedef __attribute__((ext_vector_type(4))) short short4v;
typedef __attribute__((ext_vector_type(4))) float f32x4;

#define LDK 40   // padded K-stride in bf16 elems (32 data + 8 pad)

// h = x @ W0^T : x [N,256] f32, W0 [256,256] f32 row-major (row c = out ch c).
// Split-precision bf16 MFMA: x=xh+xl, W=wh+wl, h ~= xh*wh + xh*wl + xl*wh.
// Tile: BM=128 x BN=256 (full width, x fetched once), BK=32, 512 thr (8 waves,
// wave grid 2x4, 64x64 per wave as 4x4 16x16x32 fragments).
__global__ __launch_bounds__(512, 2) void gemm_h(const float* __restrict__ x,
                                                 const float* __restrict__ W,
                                                 float* __restrict__ h, int N) {
    __shared__ short Ah[128 * LDK];
    __shared__ short Al[128 * LDK];
    __shared__ short Bh[256 * LDK];
    __shared__ short Bl[256 * LDK];

    int tid = threadIdx.x;
    int brow = blockIdx.x * 128;
    int w = tid >> 6, lane = tid & 63;
    int wr = w >> 2, wc = w & 3;            // wave quadrant: rows wr*64, cols wc*64
    int lrow = lane & 15, kblk = lane >> 4; // fragment lane mapping

    f32x4 acc[4][4] = {};

    for (int kc = 0; kc < 256; kc += 32) {
        // stage A tile (128x32 f32 -> split bf16 hi/lo), 2 float4 per thread
#pragma unroll
        for (int v = 0; v < 2; ++v) {
            int idx = tid + v * 512;        // 0..1023
            int r = idx >> 3, c4 = idx & 7;
            int grow = brow + r;
            float4 val = make_float4(0.f, 0.f, 0.f, 0.f);
            if (grow < N) val = *(const float4*)(x + (size_t)grow * NFEAT + kc + c4 * 4);
            float f[4] = {val.x, val.y, val.z, val.w};
            short4v hi, lo;
#pragma unroll
            for (int j = 0; j < 4; ++j) {
                __hip_bfloat16 hb = __float2bfloat16(f[j]);
                __hip_bfloat16 lb = __float2bfloat16(f[j] - __bfloat162float(hb));
                hi[j] = __hip_bfloat16_raw(hb).x;
                lo[j] = __hip_bfloat16_raw(lb).x;
            }
            *(short4v*)&Ah[r * LDK + c4 * 4] = hi;
            *(short4v*)&Al[r * LDK + c4 * 4] = lo;
        }
        // stage B tile (256x32 f32 -> split bf16 hi/lo), 4 float4 per thread
#pragma unroll
        for (int v = 0; v < 4; ++v) {
            int idx = tid + v * 512;        // 0..2047
            int r = idx >> 3, c4 = idx & 7;
            float4 val = *(const float4*)(W + (size_t)r * NFEAT + kc + c4 * 4);
            float f[4] = {val.x, val.y, val.z, val.w};
            short4v hi, lo;
#pragma unroll
            for (int j = 0; j < 4; ++j) {
                __hip_bfloat16 hb = __float2bfloat16(f[j]);
                __hip_bfloat16 lb = __float2bfloat16(f[j] - __bfloat162float(hb));
                hi[j] = __hip_bfloat16_raw(hb).x;
                lo[j] = __hip_bfloat16_raw(lb).x;
            }
            *(short4v*)&Bh[r * LDK + c4 * 4] = hi;
            *(short4v*)&Bl[r * LDK + c4 * 4] = lo;
        }
        __syncthreads();

        short8v ah[4], al[4], bh[4], bl[4];
#pragma unroll
        for (int i = 0; i < 4; ++i) {
            int ar = wr * 64 + i * 16 + lrow;
            ah[i] = *(short8v*)&Ah[ar * LDK + kblk * 8];
            al[i] = *(short8v*)&Al[ar * LDK + kblk * 8];
            int bc = wc * 64 + i * 16 + lrow;
            bh[i] = *(short8v*)&Bh[bc * LDK + kblk * 8];
            bl[i] = *(short8v*)&Bl[bc * LDK + kblk * 8];
        }
#pragma unroll
        for (int i = 0; i < 4; ++i)
#pragma unroll
            for (int j = 0; j < 4; ++j) {
                acc[i][j] = __builtin_amdgcn_mfma_f32_16x16x32_bf16(ah[i], bh[j], acc[i][j], 0, 0, 0);
                acc[i][j] = __builtin_amdgcn_mfma_f32_16x16x32_bf16(ah[i], bl[j], acc[i][j], 0, 0, 0);
                acc[i][j] = __builtin_amdgcn_mfma_f32_16x16x32_bf16(al[i], bh[j], acc[i][j], 0, 0, 0);
            }
        __syncthreads();
    }

    // epilogue: C/D layout col=lane&15, row=(lane>>4)*4+reg  [m89-verified]
#pragma unroll
    for (int i = 0; i < 4; ++i) {
#pragma unroll
        for (int r = 0; r < 4; ++r) {
            int grow = brow + wr * 64 + i * 16 + (lane >> 4) * 4 + r;
            if (grow < N) {
#pragma unroll
                for (int j = 0; j < 4; ++j) {
                    int col = wc * 64 + j * 16 + (lane & 15);
                    h[(size_t)grow * NFEAT + col] = acc[i][j][r];
                }
            }
        }
    }
}

// a_s[n][hd] = sum_f h[n][hd*32+f]*att_s[hd*32+f]; same for a_d.
__global__ __launch_bounds__(256) void asad_kernel(const float* __restrict__ h,
                                                   const float* __restrict__ att_s,
                                                   const float* __restrict__ att_d,
                                                   float* __restrict__ a_s,
                                                   float* __restrict__ a_d, int N) {
    int n = blockIdx.x, t = threadIdx.x;
    float hv = h[(size_t)n * NFEAT + t];
    float ps = hv * att_s[t];
    float pd = hv * att_d[t];
#pragma unroll
    for (int off = 16; off; off >>= 1) {
        ps += __shfl_xor(ps, off, 32);
        pd += __shfl_xor(pd, off, 32);
    }
    if ((t & 31) == 0) {
        int hd = t >> 5;
        a_s[n * NHEADS + hd] = ps;
        a_d[n * NHEADS + hd] = pd;
    }
}

__global__ void count_kernel(const int* __restrict__ ei, int* __restrict__ counts, int E) {
    int e = blockIdx.x * 256 + threadIdx.x;
    if (e < E) atomicAdd(&counts[ei[E + e]], 1);
}

// exclusive scan of counts[0..n) -> offsets[0..n], plus copy into cursor.
__global__ __launch_bounds__(1024) void scan_kernel(const int* __restrict__ counts,
                                                    int* __restrict__ offsets,
                                                    int* __restrict__ cursor, int n) {
    int t = threadIdx.x;
    __shared__ int waveTot[16];
    __shared__ int s_carry;
    if (t == 0) s_carry = 0;
    __syncthreads();
    for (int base = 0; base < n; base += 4096) {
        int idx = base + t * 4;
        int a = 0, b = 0, c = 0, d = 0;
        if (idx + 3 < n) {
            int4 v = *(const int4*)(counts + idx);
            a = v.x; b = v.y; c = v.z; d = v.w;
        } else {
            if (idx < n) a = counts[idx];
            if (idx + 1 < n) b = counts[idx + 1];
            if (idx + 2 < n) c = counts[idx + 2];
            if (idx + 3 < n) d = counts[idx + 3];
        }
        int s0 = a, s1 = s0 + b, s2 = s1 + c, s3 = s2 + d;
        int lane = t & 63, wid = t >> 6;
        int incl = s3;
#pragma unroll
        for (int off = 1; off < 64; off <<= 1) {
            int u = __shfl_up(incl, off, 64);
            if (lane >= off) incl += u;
        }
        if (lane == 63) waveTot[wid] = incl;
        __syncthreads();
        int wpre = 0;
        for (int w = 0; w < wid; ++w) wpre += waveTot[w];
        int pre = s_carry + wpre + incl - s3;  // exclusive prefix for this thread's 1st elem
        if (idx < n)     { offsets[idx] = pre;          cursor[idx] = pre; }
        if (idx + 1 < n) { offsets[idx + 1] = pre + s0; cursor[idx + 1] = pre + s0; }
        if (idx + 2 < n) { offsets[idx + 2] = pre + s1; cursor[idx + 2] = pre + s1; }
        if (idx + 3 < n) { offsets[idx + 3] = pre + s2; cursor[idx + 3] = pre + s2; }
        __syncthreads();
        if (t == 1023) s_carry = s_carry + wpre + incl;
        __syncthreads();
    }
    if (t == 0) offsets[n] = s_carry;
}

__global__ void fill_kernel(const int* __restrict__ ei, int* __restrict__ cursor,
                            int* __restrict__ csr_src, int E) {
    int e = blockIdx.x * 256 + threadIdx.x;
    if (e < E) {
        int d = ei[E + e];
        int pos = atomicAdd(&cursor[d], 1);
        csr_src[pos] = ei[e];
    }
}

__device__ __forceinline__ float leaky02(float x) { return x >= 0.f ? x : 0.2f * x; }

// One block (256 thr) per destination node: softmax over incoming edges
// (+ self loop), then gather-aggregate alpha*h[src], then ELU(+bias).
__global__ __launch_bounds__(256) void aggregate_kernel(
    const float* __restrict__ h, const float* __restrict__ a_s,
    const float* __restrict__ a_d, const int* __restrict__ offsets,
    const int* __restrict__ csr_src, const float* __restrict__ b0,
    float* __restrict__ out, int N) {
    int n = blockIdx.x;
    int t = threadIdx.x;
    int start = offsets[n];
    int deg = offsets[n + 1] - start;
    int tdeg = deg + 1;  // virtual self loop at index == deg

    __shared__ float s_m[NHEADS], s_inv[NHEADS];
    __shared__ float s_alpha[TE][NHEADS];
    __shared__ int s_src[TE];
    __shared__ float s_part[4][NFEAT];

    int g = t >> 5, gl = t & 31;
    float ad = a_d[n * NHEADS + g];

    // phase 1: per-head max then denom (streaming, 32-lane groups)
    float mloc = -3.4e38f;
    for (int i = gl; i < tdeg; i += 32) {
        int s = (i < deg) ? csr_src[start + i] : n;
        float l = leaky02(a_s[s * NHEADS + g] + ad);
        mloc = fmaxf(mloc, l);
    }
#pragma unroll
    for (int off = 16; off; off >>= 1) mloc = fmaxf(mloc, __shfl_xor(mloc, off, 32));
    float dloc = 0.f;
    for (int i = gl; i < tdeg; i += 32) {
        int s = (i < deg) ? csr_src[start + i] : n;
        float l = leaky02(a_s[s * NHEADS + g] + ad);
        dloc += __expf(l - mloc);
    }
#pragma unroll
    for (int off = 16; off; off >>= 1) dloc += __shfl_xor(dloc, off, 32);
    if (gl == 0) {
        s_m[g] = mloc;
        s_inv[g] = 1.f / (dloc + 1e-16f);
    }
    __syncthreads();

    // phase 2: tiled alpha computation + float4 gather-accumulate
    int et = t >> 6;       // 4 edge-parallel groups
    int f4 = t & 63;       // feature quad [f4*4, f4*4+4)
    int hd4 = f4 >> 3;     // head of this quad
    float4 acc = make_float4(0.f, 0.f, 0.f, 0.f);
    for (int tb = 0; tb < tdeg; tb += TE) {
        int tn = min(TE, tdeg - tb);
        __syncthreads();  // protect s_alpha/s_src reuse
        for (int w = t; w < tn * NHEADS; w += 256) {
            int e = w >> 3, hd = w & 7;
            int i = tb + e;
            int s = (i < deg) ? csr_src[start + i] : n;
            if (hd == 0) s_src[e] = s;
            float l = leaky02(a_s[s * NHEADS + hd] + a_d[n * NHEADS + hd]);
            s_alpha[e][hd] = __expf(l - s_m[hd]) * s_inv[hd];
        }
        __syncthreads();
        for (int e = et; e < tn; e += 4) {
            int s = s_src[e];
            float al = s_alpha[e][hd4];
            float4 hv = *(const float4*)(h + (size_t)s * NFEAT + f4 * 4);
            acc.x += al * hv.x;
            acc.y += al * hv.y;
            acc.z += al * hv.z;
            acc.w += al * hv.w;
        }
    }
    s_part[et][f4 * 4 + 0] = acc.x;
    s_part[et][f4 * 4 + 1] = acc.y;
    s_part[et][f4 * 4 + 2] = acc.z;
    s_part[et][f4 * 4 + 3] = acc.w;
    __syncthreads();
    float tot = s_part[0][t] + s_part[1][t] + s_part[2][t] + s_part[3][t];
    tot += b0[t];
    out[(size_t)n * NFEAT + t] = tot > 0.f ? tot : (__expf(tot) - 1.f);
}

extern "C" void kernel_launch(void* const* d_in, const int* in_sizes, int n_in,
                              void* d_out, int out_size, void* d_ws, size_t ws_size,
                              hipStream_t stream) {
    const float* x     = (const float*)d_in[0];
    const int*   ei    = (const int*)d_in[1];
    const float* W0    = (const float*)d_in[2];
    const float* att_s = (const float*)d_in[3];
    const float* att_d = (const float*)d_in[4];
    const float* b0    = (const float*)d_in[5];
    float* out = (float*)d_out;

    int N = in_sizes[0] / NFEAT;  // 50000
    int E = in_sizes[1] / 2;      // 800000

    char* base = (char*)d_ws;
    size_t off = 0;
    auto nxt = [&](size_t bytes) -> void* {
        void* p = base + off;
        off = (off + bytes + 255) & ~(size_t)255;
        return p;
    };
    float* h       = (float*)nxt(sizeof(float) * (size_t)N * NFEAT);
    float* a_s     = (float*)nxt(sizeof(float) * (size_t)N * NHEADS);
    float* a_d     = (float*)nxt(sizeof(float) * (size_t)N * NHEADS);
    int*   counts  = (int*)nxt(sizeof(int) * N);
    int*   offsets = (int*)nxt(sizeof(int) * (N + 1));
    int*   cursor  = (int*)nxt(sizeof(int) * N);
    int*   csr     = (int*)nxt(sizeof(int) * E);

    hipMemsetAsync(counts, 0, sizeof(int) * N, stream);

    gemm_h<<<dim3((N + 127) / 128), 512, 0, stream>>>(x, W0, h, N);
    asad_kernel<<<N, 256, 0, stream>>>(h, att_s, att_d, a_s, a_d, N);
    count_kernel<<<(E + 255) / 256, 256, 0, stream>>>(ei, counts, E);
    scan_kernel<<<1, 1024, 0, stream>>>(counts, offsets, cursor, N);
    fill_kernel<<<(E + 255) / 256, 256, 0, stream>>>(ei, cursor, csr, E);
    aggregate_kernel<<<N, 256, 0, stream>>>(h, a_s, a_d, offsets, csr, b0, out, N);
}

// Round 3
// 303.755 us; speedup vs baseline: 1.4589x; 1.1392x over previous
//
#include <hip/hip_runtime.h>
#include <hip/hip_bf16.h>

// ---------------------------------------------------------------------------
// GAT layer 0 only: reference returns outputs[-2] == elu(GATConv0(x)).
// Pipeline: gemm_h (bf16-MFMA split precision, fused a_s/a_d epilogue,
//           writes h in bf16) -> CSR (count/scan/fill) -> aggregate (bf16
//           gather, f32 accumulate).
// ---------------------------------------------------------------------------

#define NFEAT 256   // HEADS*HID == D_IN == 256
#define NHEADS 8
#define TE 128      // alpha tile (edges) staged in LDS

typedef __attribute__((ext_vector_type(8))) short short8v;
typedef __attribute__((ext_vector_type(4))) short short4v;
typedef __attribute__((ext_vector_type(4))) float f32x4;

#define LDK 40   // padded K-stride in bf16 elems (32 data + 8 pad)

__device__ __forceinline__ float bf2f(unsigned short u) {
    union { float f; unsigned int i; } v;
    v.i = ((unsigned int)u) << 16;
    return v.f;
}

// h = x @ W0^T : x [N,256] f32, W0 [256,256] f32 row-major (row c = out ch c).
// Split-precision bf16 MFMA: x=xh+xl, W=wh+wl, h ~= xh*wh + xh*wl + xl*wh.
// Tile: BM=128 x BN=256 (full width), BK=32, 512 thr (8 waves, 2x4 wave grid,
// 64x64 per wave as 4x4 16x16x32 fragments).
// Epilogue: writes h as bf16, and a_s/a_d (exact f32, from accumulators).
__global__ __launch_bounds__(512, 2) void gemm_h(const float* __restrict__ x,
                                                 const float* __restrict__ W,
                                                 const float* __restrict__ att_s,
                                                 const float* __restrict__ att_d,
                                                 unsigned short* __restrict__ hb,
                                                 float* __restrict__ a_s,
                                                 float* __restrict__ a_d, int N) {
    __shared__ short Ah[128 * LDK];
    __shared__ short Al[128 * LDK];
    __shared__ short Bh[256 * LDK];
    __shared__ short Bl[256 * LDK];

    int tid = threadIdx.x;
    int brow = blockIdx.x * 128;
    int w = tid >> 6, lane = tid & 63;
    int wr = w >> 2, wc = w & 3;            // wave quadrant: rows wr*64, cols wc*64
    int lrow = lane & 15, kblk = lane >> 4; // fragment lane mapping

    f32x4 acc[4][4] = {};

    for (int kc = 0; kc < 256; kc += 32) {
        // stage A tile (128x32 f32 -> split bf16 hi/lo), 2 float4 per thread
#pragma unroll
        for (int v = 0; v < 2; ++v) {
            int idx = tid + v * 512;        // 0..1023
            int r = idx >> 3, c4 = idx & 7;
            int grow = brow + r;
            float4 val = make_float4(0.f, 0.f, 0.f, 0.f);
            if (grow < N) val = *(const float4*)(x + (size_t)grow * NFEAT + kc + c4 * 4);
            float f[4] = {val.x, val.y, val.z, val.w};
            short4v hi, lo;
#pragma unroll
            for (int j = 0; j < 4; ++j) {
                __hip_bfloat16 hbv = __float2bfloat16(f[j]);
                __hip_bfloat16 lbv = __float2bfloat16(f[j] - __bfloat162float(hbv));
                hi[j] = __hip_bfloat16_raw(hbv).x;
                lo[j] = __hip_bfloat16_raw(lbv).x;
            }
            *(short4v*)&Ah[r * LDK + c4 * 4] = hi;
            *(short4v*)&Al[r * LDK + c4 * 4] = lo;
        }
        // stage B tile (256x32 f32 -> split bf16 hi/lo), 4 float4 per thread
#pragma unroll
        for (int v = 0; v < 4; ++v) {
            int idx = tid + v * 512;        // 0..2047
            int r = idx >> 3, c4 = idx & 7;
            float4 val = *(const float4*)(W + (size_t)r * NFEAT + kc + c4 * 4);
            float f[4] = {val.x, val.y, val.z, val.w};
            short4v hi, lo;
#pragma unroll
            for (int j = 0; j < 4; ++j) {
                __hip_bfloat16 hbv = __float2bfloat16(f[j]);
                __hip_bfloat16 lbv = __float2bfloat16(f[j] - __bfloat162float(hbv));
                hi[j] = __hip_bfloat16_raw(hbv).x;
                lo[j] = __hip_bfloat16_raw(lbv).x;
            }
            *(short4v*)&Bh[r * LDK + c4 * 4] = hi;
            *(short4v*)&Bl[r * LDK + c4 * 4] = lo;
        }
        __syncthreads();

        short8v ah[4], al[4], bh[4], bl[4];
#pragma unroll
        for (int i = 0; i < 4; ++i) {
            int ar = wr * 64 + i * 16 + lrow;
            ah[i] = *(short8v*)&Ah[ar * LDK + kblk * 8];
            al[i] = *(short8v*)&Al[ar * LDK + kblk * 8];
            int bc = wc * 64 + i * 16 + lrow;
            bh[i] = *(short8v*)&Bh[bc * LDK + kblk * 8];
            bl[i] = *(short8v*)&Bl[bc * LDK + kblk * 8];
        }
#pragma unroll
        for (int i = 0; i < 4; ++i)
#pragma unroll
            for (int j = 0; j < 4; ++j) {
                acc[i][j] = __builtin_amdgcn_mfma_f32_16x16x32_bf16(ah[i], bh[j], acc[i][j], 0, 0, 0);
                acc[i][j] = __builtin_amdgcn_mfma_f32_16x16x32_bf16(ah[i], bl[j], acc[i][j], 0, 0, 0);
                acc[i][j] = __builtin_amdgcn_mfma_f32_16x16x32_bf16(al[i], bh[j], acc[i][j], 0, 0, 0);
            }
        __syncthreads();
    }

    // C/D layout: col=lane&15, row=(lane>>4)*4+reg  [m89-verified]
    int lc = lane & 15, lq = lane >> 4;

    // att coefficients for this thread's 4 columns (same for every row)
    float ats[4], atd[4];
#pragma unroll
    for (int j = 0; j < 4; ++j) {
        int col = wc * 64 + j * 16 + lc;
        ats[j] = att_s[col];
        atd[j] = att_d[col];
    }

#pragma unroll
    for (int i = 0; i < 4; ++i) {
#pragma unroll
        for (int r = 0; r < 4; ++r) {
            int grow = brow + wr * 64 + i * 16 + lq * 4 + r;
            // h (bf16) write
            if (grow < N) {
#pragma unroll
                for (int j = 0; j < 4; ++j) {
                    int col = wc * 64 + j * 16 + lc;
                    hb[(size_t)grow * NFEAT + col] =
                        __hip_bfloat16_raw(__float2bfloat16(acc[i][j][r])).x;
                }
            }
            // a_s/a_d partials: head = wc*2 + (j>>1); reduce over 16 lanes (lc)
            float ps0 = acc[i][0][r] * ats[0] + acc[i][1][r] * ats[1];
            float ps1 = acc[i][2][r] * ats[2] + acc[i][3][r] * ats[3];
            float pd0 = acc[i][0][r] * atd[0] + acc[i][1][r] * atd[1];
            float pd1 = acc[i][2][r] * atd[2] + acc[i][3][r] * atd[3];
#pragma unroll
            for (int off = 8; off; off >>= 1) {
                ps0 += __shfl_xor(ps0, off, 16);
                ps1 += __shfl_xor(ps1, off, 16);
                pd0 += __shfl_xor(pd0, off, 16);
                pd1 += __shfl_xor(pd1, off, 16);
            }
            if (lc == 0 && grow < N) {
                a_s[grow * NHEADS + wc * 2 + 0] = ps0;
                a_s[grow * NHEADS + wc * 2 + 1] = ps1;
                a_d[grow * NHEADS + wc * 2 + 0] = pd0;
                a_d[grow * NHEADS + wc * 2 + 1] = pd1;
            }
        }
    }
}

__global__ void count_kernel(const int* __restrict__ ei, int* __restrict__ counts, int E) {
    int e = blockIdx.x * 256 + threadIdx.x;
    if (e < E) atomicAdd(&counts[ei[E + e]], 1);
}

// exclusive scan of counts[0..n) -> offsets[0..n], plus copy into cursor.
__global__ __launch_bounds__(1024) void scan_kernel(const int* __restrict__ counts,
                                                    int* __restrict__ offsets,
                                                    int* __restrict__ cursor, int n) {
    int t = threadIdx.x;
    __shared__ int waveTot[16];
    __shared__ int s_carry;
    if (t == 0) s_carry = 0;
    __syncthreads();
    for (int base = 0; base < n; base += 4096) {
        int idx = base + t * 4;
        int a = 0, b = 0, c = 0, d = 0;
        if (idx + 3 < n) {
            int4 v = *(const int4*)(counts + idx);
            a = v.x; b = v.y; c = v.z; d = v.w;
        } else {
            if (idx < n) a = counts[idx];
            if (idx + 1 < n) b = counts[idx + 1];
            if (idx + 2 < n) c = counts[idx + 2];
            if (idx + 3 < n) d = counts[idx + 3];
        }
        int s0 = a, s1 = s0 + b, s2 = s1 + c, s3 = s2 + d;
        int lane = t & 63, wid = t >> 6;
        int incl = s3;
#pragma unroll
        for (int off = 1; off < 64; off <<= 1) {
            int u = __shfl_up(incl, off, 64);
            if (lane >= off) incl += u;
        }
        if (lane == 63) waveTot[wid] = incl;
        __syncthreads();
        int wpre = 0;
        for (int w = 0; w < wid; ++w) wpre += waveTot[w];
        int pre = s_carry + wpre + incl - s3;  // exclusive prefix for this thread's 1st elem
        if (idx < n)     { offsets[idx] = pre;          cursor[idx] = pre; }
        if (idx + 1 < n) { offsets[idx + 1] = pre + s0; cursor[idx + 1] = pre + s0; }
        if (idx + 2 < n) { offsets[idx + 2] = pre + s1; cursor[idx + 2] = pre + s1; }
        if (idx + 3 < n) { offsets[idx + 3] = pre + s2; cursor[idx + 3] = pre + s2; }
        __syncthreads();
        if (t == 1023) s_carry = s_carry + wpre + incl;
        __syncthreads();
    }
    if (t == 0) offsets[n] = s_carry;
}

__global__ void fill_kernel(const int* __restrict__ ei, int* __restrict__ cursor,
                            int* __restrict__ csr_src, int E) {
    int e = blockIdx.x * 256 + threadIdx.x;
    if (e < E) {
        int d = ei[E + e];
        int pos = atomicAdd(&cursor[d], 1);
        csr_src[pos] = ei[e];
    }
}

__device__ __forceinline__ float leaky02(float x) { return x >= 0.f ? x : 0.2f * x; }

// One block (256 thr) per destination node: softmax over incoming edges
// (+ self loop), then gather-aggregate alpha*h_bf16[src], then ELU(+bias).
// 32 threads per row (8 bf16 feats each), 8 edge-parallel groups.
__global__ __launch_bounds__(256) void aggregate_kernel(
    const unsigned short* __restrict__ hb, const float* __restrict__ a_s,
    const float* __restrict__ a_d, const int* __restrict__ offsets,
    const int* __restrict__ csr_src, const float* __restrict__ b0,
    float* __restrict__ out, int N) {
    int n = blockIdx.x;
    int t = threadIdx.x;
    int start = offsets[n];
    int deg = offsets[n + 1] - start;
    int tdeg = deg + 1;  // virtual self loop at index == deg

    __shared__ float s_m[NHEADS], s_inv[NHEADS];
    __shared__ float s_alpha[TE][NHEADS];
    __shared__ int s_src[TE];
    __shared__ float s_part[8][NFEAT];

    int g = t >> 5, gl = t & 31;
    float ad = a_d[n * NHEADS + g];

    // phase 1: per-head max then denom (streaming, 32-lane groups; head g)
    float mloc = -3.4e38f;
    for (int i = gl; i < tdeg; i += 32) {
        int s = (i < deg) ? csr_src[start + i] : n;
        float l = leaky02(a_s[s * NHEADS + g] + ad);
        mloc = fmaxf(mloc, l);
    }
#pragma unroll
    for (int off = 16; off; off >>= 1) mloc = fmaxf(mloc, __shfl_xor(mloc, off, 32));
    float dloc = 0.f;
    for (int i = gl; i < tdeg; i += 32) {
        int s = (i < deg) ? csr_src[start + i] : n;
        float l = leaky02(a_s[s * NHEADS + g] + ad);
        dloc += __expf(l - mloc);
    }
#pragma unroll
    for (int off = 16; off; off >>= 1) dloc += __shfl_xor(dloc, off, 32);
    if (gl == 0) {
        s_m[g] = mloc;
        s_inv[g] = 1.f / (dloc + 1e-16f);
    }
    __syncthreads();

    // phase 2: tiled alpha computation + bf16x8 gather-accumulate
    int et = t >> 5;       // 8 edge-parallel groups
    int f8 = t & 31;       // feature octet [f8*8, f8*8+8)
    int hd8 = f8 >> 2;     // head of this octet
    float acc[8] = {};
    for (int tb = 0; tb < tdeg; tb += TE) {
        int tn = min(TE, tdeg - tb);
        __syncthreads();  // protect s_alpha/s_src reuse
        for (int wk = t; wk < tn * NHEADS; wk += 256) {
            int e = wk >> 3, hd = wk & 7;
            int i = tb + e;
            int s = (i < deg) ? csr_src[start + i] : n;
            if (hd == 0) s_src[e] = s;
            float l = leaky02(a_s[s * NHEADS + hd] + a_d[n * NHEADS + hd]);
            s_alpha[e][hd] = __expf(l - s_m[hd]) * s_inv[hd];
        }
        __syncthreads();
        for (int e = et; e < tn; e += 8) {
            int s = s_src[e];
            float al = s_alpha[e][hd8];
            short8v hv = *(const short8v*)(hb + (size_t)s * NFEAT + f8 * 8);
#pragma unroll
            for (int k = 0; k < 8; ++k)
                acc[k] += al * bf2f((unsigned short)hv[k]);
        }
    }
#pragma unroll
    for (int k = 0; k < 8; ++k) s_part[et][f8 * 8 + k] = acc[k];
    __syncthreads();
    float tot = 0.f;
#pragma unroll
    for (int gblk = 0; gblk < 8; ++gblk) tot += s_part[gblk][t];
    tot += b0[t];
    out[(size_t)n * NFEAT + t] = tot > 0.f ? tot : (__expf(tot) - 1.f);
}

extern "C" void kernel_launch(void* const* d_in, const int* in_sizes, int n_in,
                              void* d_out, int out_size, void* d_ws, size_t ws_size,
                              hipStream_t stream) {
    const float* x     = (const float*)d_in[0];
    const int*   ei    = (const int*)d_in[1];
    const float* W0    = (const float*)d_in[2];
    const float* att_s = (const float*)d_in[3];
    const float* att_d = (const float*)d_in[4];
    const float* b0    = (const float*)d_in[5];
    float* out = (float*)d_out;

    int N = in_sizes[0] / NFEAT;  // 50000
    int E = in_sizes[1] / 2;      // 800000

    char* base = (char*)d_ws;
    size_t off = 0;
    auto nxt = [&](size_t bytes) -> void* {
        void* p = base + off;
        off = (off + bytes + 255) & ~(size_t)255;
        return p;
    };
    unsigned short* hb = (unsigned short*)nxt(sizeof(unsigned short) * (size_t)N * NFEAT);
    float* a_s     = (float*)nxt(sizeof(float) * (size_t)N * NHEADS);
    float* a_d     = (float*)nxt(sizeof(float) * (size_t)N * NHEADS);
    int*   counts  = (int*)nxt(sizeof(int) * N);
    int*   offsets = (int*)nxt(sizeof(int) * (N + 1));
    int*   cursor  = (int*)nxt(sizeof(int) * N);
    int*   csr     = (int*)nxt(sizeof(int) * E);

    hipMemsetAsync(counts, 0, sizeof(int) * N, stream);

    gemm_h<<<dim3((N + 127) / 128), 512, 0, stream>>>(x, W0, att_s, att_d, hb, a_s, a_d, N);
    count_kernel<<<(E + 255) / 256, 256, 0, stream>>>(ei, counts, E);
    scan_kernel<<<1, 1024, 0, stream>>>(counts, offsets, cursor, N);
    fill_kernel<<<(E + 255) / 256, 256, 0, stream>>>(ei, cursor, csr, E);
    aggregate_kernel<<<N, 256, 0, stream>>>(hb, a_s, a_d, offsets, csr, b0, out, N);
}

// Round 4
// 241.575 us; speedup vs baseline: 1.8344x; 1.2574x over previous
//
#include <hip/hip_runtime.h>
#include <hip/hip_bf16.h>

// ---------------------------------------------------------------------------
// GAT layer 0 only: reference returns outputs[-2] == elu(GATConv0(x)).
// Pipeline: gemm_h (bf16-MFMA split precision, fused a_s/a_d epilogue, bf16 h)
//        -> count/scan -> fill (CSR + fused edge weights w=exp(leaky(...)))
//        -> aggregate (wave-per-node single pass: num=Σw·h, den=Σw, out=num/den)
// Softmax without max-subtraction: logits ~N(0,2), |l|<~9 over 6.8M samples,
// exp(l) far from f32 overflow; alpha identical to max-subtracted form.
// ---------------------------------------------------------------------------

#define NFEAT 256   // HEADS*HID == D_IN == 256
#define NHEADS 8

typedef __attribute__((ext_vector_type(8))) short short8v;
typedef __attribute__((ext_vector_type(4))) short short4v;
typedef __attribute__((ext_vector_type(4))) float f32x4;

#define LDK 40   // padded K-stride in bf16 elems (32 data + 8 pad)

__device__ __forceinline__ float bf2f(unsigned short u) {
    union { float f; unsigned int i; } v;
    v.i = ((unsigned int)u) << 16;
    return v.f;
}

__device__ __forceinline__ float leaky02(float x) { return x >= 0.f ? x : 0.2f * x; }

// h = x @ W0^T : x [N,256] f32, W0 [256,256] f32 row-major (row c = out ch c).
// Split-precision bf16 MFMA: x=xh+xl, W=wh+wl, h ~= xh*wh + xh*wl + xl*wh.
// Tile: BM=128 x BN=256 (full width), BK=32, 512 thr (8 waves, 2x4 wave grid,
// 64x64 per wave as 4x4 16x16x32 fragments).
// Epilogue: writes h as bf16, and a_s/a_d (exact f32, from accumulators).
__global__ __launch_bounds__(512, 2) void gemm_h(const float* __restrict__ x,
                                                 const float* __restrict__ W,
                                                 const float* __restrict__ att_s,
                                                 const float* __restrict__ att_d,
                                                 unsigned short* __restrict__ hb,
                                                 float* __restrict__ a_s,
                                                 float* __restrict__ a_d, int N) {
    __shared__ short Ah[128 * LDK];
    __shared__ short Al[128 * LDK];
    __shared__ short Bh[256 * LDK];
    __shared__ short Bl[256 * LDK];

    int tid = threadIdx.x;
    int brow = blockIdx.x * 128;
    int w = tid >> 6, lane = tid & 63;
    int wr = w >> 2, wc = w & 3;            // wave quadrant: rows wr*64, cols wc*64
    int lrow = lane & 15, kblk = lane >> 4; // fragment lane mapping

    f32x4 acc[4][4] = {};

    for (int kc = 0; kc < 256; kc += 32) {
        // stage A tile (128x32 f32 -> split bf16 hi/lo), 2 float4 per thread
#pragma unroll
        for (int v = 0; v < 2; ++v) {
            int idx = tid + v * 512;        // 0..1023
            int r = idx >> 3, c4 = idx & 7;
            int grow = brow + r;
            float4 val = make_float4(0.f, 0.f, 0.f, 0.f);
            if (grow < N) val = *(const float4*)(x + (size_t)grow * NFEAT + kc + c4 * 4);
            float f[4] = {val.x, val.y, val.z, val.w};
            short4v hi, lo;
#pragma unroll
            for (int j = 0; j < 4; ++j) {
                __hip_bfloat16 hbv = __float2bfloat16(f[j]);
                __hip_bfloat16 lbv = __float2bfloat16(f[j] - __bfloat162float(hbv));
                hi[j] = __hip_bfloat16_raw(hbv).x;
                lo[j] = __hip_bfloat16_raw(lbv).x;
            }
            *(short4v*)&Ah[r * LDK + c4 * 4] = hi;
            *(short4v*)&Al[r * LDK + c4 * 4] = lo;
        }
        // stage B tile (256x32 f32 -> split bf16 hi/lo), 4 float4 per thread
#pragma unroll
        for (int v = 0; v < 4; ++v) {
            int idx = tid + v * 512;        // 0..2047
            int r = idx >> 3, c4 = idx & 7;
            float4 val = *(const float4*)(W + (size_t)r * NFEAT + kc + c4 * 4);
            float f[4] = {val.x, val.y, val.z, val.w};
            short4v hi, lo;
#pragma unroll
            for (int j = 0; j < 4; ++j) {
                __hip_bfloat16 hbv = __float2bfloat16(f[j]);
                __hip_bfloat16 lbv = __float2bfloat16(f[j] - __bfloat162float(hbv));
                hi[j] = __hip_bfloat16_raw(hbv).x;
                lo[j] = __hip_bfloat16_raw(lbv).x;
            }
            *(short4v*)&Bh[r * LDK + c4 * 4] = hi;
            *(short4v*)&Bl[r * LDK + c4 * 4] = lo;
        }
        __syncthreads();

        short8v ah[4], al[4], bh[4], bl[4];
#pragma unroll
        for (int i = 0; i < 4; ++i) {
            int ar = wr * 64 + i * 16 + lrow;
            ah[i] = *(short8v*)&Ah[ar * LDK + kblk * 8];
            al[i] = *(short8v*)&Al[ar * LDK + kblk * 8];
            int bc = wc * 64 + i * 16 + lrow;
            bh[i] = *(short8v*)&Bh[bc * LDK + kblk * 8];
            bl[i] = *(short8v*)&Bl[bc * LDK + kblk * 8];
        }
#pragma unroll
        for (int i = 0; i < 4; ++i)
#pragma unroll
            for (int j = 0; j < 4; ++j) {
                acc[i][j] = __builtin_amdgcn_mfma_f32_16x16x32_bf16(ah[i], bh[j], acc[i][j], 0, 0, 0);
                acc[i][j] = __builtin_amdgcn_mfma_f32_16x16x32_bf16(ah[i], bl[j], acc[i][j], 0, 0, 0);
                acc[i][j] = __builtin_amdgcn_mfma_f32_16x16x32_bf16(al[i], bh[j], acc[i][j], 0, 0, 0);
            }
        __syncthreads();
    }

    // C/D layout: col=lane&15, row=(lane>>4)*4+reg  [m89-verified]
    int lc = lane & 15, lq = lane >> 4;

    // att coefficients for this thread's 4 columns (same for every row)
    float ats[4], atd[4];
#pragma unroll
    for (int j = 0; j < 4; ++j) {
        int col = wc * 64 + j * 16 + lc;
        ats[j] = att_s[col];
        atd[j] = att_d[col];
    }

#pragma unroll
    for (int i = 0; i < 4; ++i) {
#pragma unroll
        for (int r = 0; r < 4; ++r) {
            int grow = brow + wr * 64 + i * 16 + lq * 4 + r;
            // h (bf16) write
            if (grow < N) {
#pragma unroll
                for (int j = 0; j < 4; ++j) {
                    int col = wc * 64 + j * 16 + lc;
                    hb[(size_t)grow * NFEAT + col] =
                        __hip_bfloat16_raw(__float2bfloat16(acc[i][j][r])).x;
                }
            }
            // a_s/a_d partials: head = wc*2 + (j>>1); reduce over 16 lanes (lc)
            float ps0 = acc[i][0][r] * ats[0] + acc[i][1][r] * ats[1];
            float ps1 = acc[i][2][r] * ats[2] + acc[i][3][r] * ats[3];
            float pd0 = acc[i][0][r] * atd[0] + acc[i][1][r] * atd[1];
            float pd1 = acc[i][2][r] * atd[2] + acc[i][3][r] * atd[3];
#pragma unroll
            for (int off = 8; off; off >>= 1) {
                ps0 += __shfl_xor(ps0, off, 16);
                ps1 += __shfl_xor(ps1, off, 16);
                pd0 += __shfl_xor(pd0, off, 16);
                pd1 += __shfl_xor(pd1, off, 16);
            }
            if (lc == 0 && grow < N) {
                a_s[grow * NHEADS + wc * 2 + 0] = ps0;
                a_s[grow * NHEADS + wc * 2 + 1] = ps1;
                a_d[grow * NHEADS + wc * 2 + 0] = pd0;
                a_d[grow * NHEADS + wc * 2 + 1] = pd1;
            }
        }
    }
}

__global__ void count_kernel(const int* __restrict__ ei, int* __restrict__ counts, int E) {
    int e = blockIdx.x * 256 + threadIdx.x;
    if (e < E) atomicAdd(&counts[ei[E + e]], 1);
}

// exclusive scan of counts[0..n) -> offsets[0..n], plus copy into cursor.
__global__ __launch_bounds__(1024) void scan_kernel(const int* __restrict__ counts,
                                                    int* __restrict__ offsets,
                                                    int* __restrict__ cursor, int n) {
    int t = threadIdx.x;
    __shared__ int waveTot[16];
    __shared__ int s_carry;
    if (t == 0) s_carry = 0;
    __syncthreads();
    for (int base = 0; base < n; base += 4096) {
        int idx = base + t * 4;
        int a = 0, b = 0, c = 0, d = 0;
        if (idx + 3 < n) {
            int4 v = *(const int4*)(counts + idx);
            a = v.x; b = v.y; c = v.z; d = v.w;
        } else {
            if (idx < n) a = counts[idx];
            if (idx + 1 < n) b = counts[idx + 1];
            if (idx + 2 < n) c = counts[idx + 2];
            if (idx + 3 < n) d = counts[idx + 3];
        }
        int s0 = a, s1 = s0 + b, s2 = s1 + c, s3 = s2 + d;
        int lane = t & 63, wid = t >> 6;
        int incl = s3;
#pragma unroll
        for (int off = 1; off < 64; off <<= 1) {
            int u = __shfl_up(incl, off, 64);
            if (lane >= off) incl += u;
        }
        if (lane == 63) waveTot[wid] = incl;
        __syncthreads();
        int wpre = 0;
        for (int w = 0; w < wid; ++w) wpre += waveTot[w];
        int pre = s_carry + wpre + incl - s3;  // exclusive prefix for this thread's 1st elem
        if (idx < n)     { offsets[idx] = pre;          cursor[idx] = pre; }
        if (idx + 1 < n) { offsets[idx + 1] = pre + s0; cursor[idx + 1] = pre + s0; }
        if (idx + 2 < n) { offsets[idx + 2] = pre + s1; cursor[idx + 2] = pre + s1; }
        if (idx + 3 < n) { offsets[idx + 3] = pre + s2; cursor[idx + 3] = pre + s2; }
        __syncthreads();
        if (t == 1023) s_carry = s_carry + wpre + incl;
        __syncthreads();
    }
    if (t == 0) offsets[n] = s_carry;
}

// CSR fill fused with edge-weight computation: w[pos][hd] = exp(leaky(a_s+a_d)).
__global__ void fill_kernel(const int* __restrict__ ei, int* __restrict__ cursor,
                            int* __restrict__ csr_src,
                            const float* __restrict__ a_s, const float* __restrict__ a_d,
                            float* __restrict__ wv, int E) {
    int e = blockIdx.x * 256 + threadIdx.x;
    if (e >= E) return;
    int s = ei[e];
    int d = ei[E + e];
    int pos = atomicAdd(&cursor[d], 1);
    csr_src[pos] = s;
    float4 as0 = *(const float4*)(a_s + (size_t)s * NHEADS);
    float4 as1 = *(const float4*)(a_s + (size_t)s * NHEADS + 4);
    float4 ad0 = *(const float4*)(a_d + (size_t)d * NHEADS);
    float4 ad1 = *(const float4*)(a_d + (size_t)d * NHEADS + 4);
    float4 w0, w1;
    w0.x = __expf(leaky02(as0.x + ad0.x));
    w0.y = __expf(leaky02(as0.y + ad0.y));
    w0.z = __expf(leaky02(as0.z + ad0.z));
    w0.w = __expf(leaky02(as0.w + ad0.w));
    w1.x = __expf(leaky02(as1.x + ad1.x));
    w1.y = __expf(leaky02(as1.y + ad1.y));
    w1.z = __expf(leaky02(as1.z + ad1.z));
    w1.w = __expf(leaky02(as1.w + ad1.w));
    *(float4*)(wv + (size_t)pos * NHEADS) = w0;
    *(float4*)(wv + (size_t)pos * NHEADS + 4) = w1;
}

// Wave-per-node aggregate: 4 nodes/block. Wave = 2 edge-groups x 32 lanes;
// lane handles 8 feats (head hd8 = (lane&31)>>2). Single pass: num += w*h,
// den += w; halves combined via shfl_xor(32); out = num/den (+bias, ELU).
__global__ __launch_bounds__(256) void aggregate_kernel(
    const unsigned short* __restrict__ hb, const float* __restrict__ a_s,
    const float* __restrict__ a_d, const int* __restrict__ offsets,
    const int* __restrict__ csr_src, const float* __restrict__ wv,
    const float* __restrict__ b0, float* __restrict__ out, int N) {
    int wid = threadIdx.x >> 6;
    int lane = threadIdx.x & 63;
    int n = blockIdx.x * 4 + wid;
    if (n >= N) return;
    int eg = lane >> 5;     // 0/1: even/odd edges
    int f8 = lane & 31;     // feature octet [f8*8, f8*8+8)
    int hd8 = f8 >> 2;      // head of this octet

    int start = offsets[n];
    int deg = offsets[n + 1] - start;

    // self-loop weight (virtual edge at i == deg)
    float sw = __expf(leaky02(a_s[(size_t)n * NHEADS + hd8] + a_d[(size_t)n * NHEADS + hd8]));

    float acc[8] = {};
    float den = 0.f;
    for (int i = eg; i < deg + 1; i += 2) {
        int s; float wq;
        if (i < deg) {
            int p = start + i;
            s = csr_src[p];
            wq = wv[(size_t)p * NHEADS + hd8];
        } else {
            s = n;
            wq = sw;
        }
        short8v hv = *(const short8v*)(hb + (size_t)s * NFEAT + f8 * 8);
#pragma unroll
        for (int k = 0; k < 8; ++k)
            acc[k] += wq * bf2f((unsigned short)hv[k]);
        den += wq;
    }
    // combine even/odd halves
#pragma unroll
    for (int k = 0; k < 8; ++k) acc[k] += __shfl_xor(acc[k], 32, 64);
    den += __shfl_xor(den, 32, 64);
    float inv = 1.f / (den + 1e-16f);

    if (eg == 0) {
        float o[8];
#pragma unroll
        for (int k = 0; k < 8; ++k) {
            float t = acc[k] * inv + b0[f8 * 8 + k];
            o[k] = t > 0.f ? t : (__expf(t) - 1.f);
        }
        float4 v0 = make_float4(o[0], o[1], o[2], o[3]);
        float4 v1 = make_float4(o[4], o[5], o[6], o[7]);
        *(float4*)(out + (size_t)n * NFEAT + f8 * 8) = v0;
        *(float4*)(out + (size_t)n * NFEAT + f8 * 8 + 4) = v1;
    }
}

extern "C" void kernel_launch(void* const* d_in, const int* in_sizes, int n_in,
                              void* d_out, int out_size, void* d_ws, size_t ws_size,
                              hipStream_t stream) {
    const float* x     = (const float*)d_in[0];
    const int*   ei    = (const int*)d_in[1];
    const float* W0    = (const float*)d_in[2];
    const float* att_s = (const float*)d_in[3];
    const float* att_d = (const float*)d_in[4];
    const float* b0    = (const float*)d_in[5];
    float* out = (float*)d_out;

    int N = in_sizes[0] / NFEAT;  // 50000
    int E = in_sizes[1] / 2;      // 800000

    char* base = (char*)d_ws;
    size_t off = 0;
    auto nxt = [&](size_t bytes) -> void* {
        void* p = base + off;
        off = (off + bytes + 255) & ~(size_t)255;
        return p;
    };
    unsigned short* hb = (unsigned short*)nxt(sizeof(unsigned short) * (size_t)N * NFEAT);
    float* a_s     = (float*)nxt(sizeof(float) * (size_t)N * NHEADS);
    float* a_d     = (float*)nxt(sizeof(float) * (size_t)N * NHEADS);
    float* wv      = (float*)nxt(sizeof(float) * (size_t)E * NHEADS);
    int*   counts  = (int*)nxt(sizeof(int) * N);
    int*   offsets = (int*)nxt(sizeof(int) * (N + 1));
    int*   cursor  = (int*)nxt(sizeof(int) * N);
    int*   csr     = (int*)nxt(sizeof(int) * E);

    hipMemsetAsync(counts, 0, sizeof(int) * N, stream);

    gemm_h<<<dim3((N + 127) / 128), 512, 0, stream>>>(x, W0, att_s, att_d, hb, a_s, a_d, N);
    count_kernel<<<(E + 255) / 256, 256, 0, stream>>>(ei, counts, E);
    scan_kernel<<<1, 1024, 0, stream>>>(counts, offsets, cursor, N);
    fill_kernel<<<(E + 255) / 256, 256, 0, stream>>>(ei, cursor, csr, a_s, a_d, wv, E);
    aggregate_kernel<<<(N + 3) / 4, 256, 0, stream>>>(hb, a_s, a_d, offsets, csr, wv, b0, out, N);
}

// Round 5
// 206.013 us; speedup vs baseline: 2.1510x; 1.1726x over previous
//
#include <hip/hip_runtime.h>
#include <hip/hip_bf16.h>

// ---------------------------------------------------------------------------
// GAT layer 0 only: reference returns outputs[-2] == elu(GATConv0(x)).
// Pipeline: wsplit (W -> bf16, K-tiled) -> gemm_h (bf16-MFMA, A split-precision,
//           fused a_s/a_d epilogue, bf16 h) -> count -> hierarchical scan
//        -> fill (CSR + fused edge weights w=exp(leaky(...)))
//        -> aggregate (wave-per-node single pass: num=Σw·h, den=Σw).
// Softmax without max-subtraction: logits ~N(0,2), |l|<~9 over 6.8M samples,
// exp(l) far from f32 overflow; alpha identical to max-subtracted form.
// ---------------------------------------------------------------------------

#define NFEAT 256   // HEADS*HID == D_IN == 256
#define NHEADS 8

typedef __attribute__((ext_vector_type(8))) short short8v;
typedef __attribute__((ext_vector_type(4))) short short4v;
typedef __attribute__((ext_vector_type(4))) float f32x4;

#define LDK 40   // padded K-stride in bf16 elems (32 data + 8 pad)

__device__ __forceinline__ float bf2f(unsigned short u) {
    union { float f; unsigned int i; } v;
    v.i = ((unsigned int)u) << 16;
    return v.f;
}

__device__ __forceinline__ float leaky02(float x) { return x >= 0.f ? x : 0.2f * x; }

// W [256,256] f32 row-major -> Wb bf16 in K-step-tiled layout:
// Wb[(kin>>5)*8192 + c*32 + (kin&31)], so each GEMM K-step's B chunk is a
// contiguous 16KB block (coalesced short8 copy, no conversion in hot loop).
__global__ __launch_bounds__(256) void wsplit_kernel(const float* __restrict__ W,
                                                     unsigned short* __restrict__ Wb) {
    int e = blockIdx.x * 256 + threadIdx.x;   // 65536 elems
    int c = e >> 8, kin = e & 255;
    float v = W[e];
    Wb[(kin >> 5) * 8192 + c * 32 + (kin & 31)] = __hip_bfloat16_raw(__float2bfloat16(v)).x;
}

// h = x @ W0^T. A split-precision (x=xh+xl), B plain bf16 (pre-converted).
// Tile: BM=64 x BN=256 (full width), BK=32, 256 thr (4 waves; wave w covers
// cols w*64 as 4x4 16x16x32 fragments over 64 rows).
// Epilogue: h as bf16, plus a_s/a_d (f32, from accumulators).
__global__ __launch_bounds__(256, 3) void gemm_h(const float* __restrict__ x,
                                                 const unsigned short* __restrict__ Wb,
                                                 const float* __restrict__ att_s,
                                                 const float* __restrict__ att_d,
                                                 unsigned short* __restrict__ hb,
                                                 float* __restrict__ a_s,
                                                 float* __restrict__ a_d, int N) {
    __shared__ short Ah[64 * LDK];
    __shared__ short Al[64 * LDK];
    __shared__ short Bh[256 * LDK];

    int tid = threadIdx.x;
    int brow = blockIdx.x * 64;
    int w = tid >> 6, lane = tid & 63;
    int lrow = lane & 15, kblk = lane >> 4; // fragment lane mapping

    f32x4 acc[4][4] = {};

    for (int kc = 0; kc < 256; kc += 32) {
        // stage A tile (64x32 f32 -> split bf16 hi/lo), 2 float4 per thread
#pragma unroll
        for (int v = 0; v < 2; ++v) {
            int idx = tid + v * 256;        // 0..511
            int r = idx >> 3, c4 = idx & 7;
            int grow = brow + r;
            float4 val = make_float4(0.f, 0.f, 0.f, 0.f);
            if (grow < N) val = *(const float4*)(x + (size_t)grow * NFEAT + kc + c4 * 4);
            float f[4] = {val.x, val.y, val.z, val.w};
            short4v hi, lo;
#pragma unroll
            for (int j = 0; j < 4; ++j) {
                __hip_bfloat16 hbv = __float2bfloat16(f[j]);
                __hip_bfloat16 lbv = __float2bfloat16(f[j] - __bfloat162float(hbv));
                hi[j] = __hip_bfloat16_raw(hbv).x;
                lo[j] = __hip_bfloat16_raw(lbv).x;
            }
            *(short4v*)&Ah[r * LDK + c4 * 4] = hi;
            *(short4v*)&Al[r * LDK + c4 * 4] = lo;
        }
        // stage B tile: contiguous 16KB chunk of pre-converted Wb, pure copy
        const unsigned short* bsrc = Wb + (kc >> 5) * 8192;
#pragma unroll
        for (int v = 0; v < 4; ++v) {
            int u = tid + v * 256;          // short8 unit 0..1023
            short8v bv = *(const short8v*)(bsrc + u * 8);
            *(short8v*)&Bh[(u >> 2) * LDK + (u & 3) * 8] = bv;
        }
        __syncthreads();

        short8v ah[4], al[4], bh[4];
#pragma unroll
        for (int i = 0; i < 4; ++i) {
            int ar = i * 16 + lrow;
            ah[i] = *(short8v*)&Ah[ar * LDK + kblk * 8];
            al[i] = *(short8v*)&Al[ar * LDK + kblk * 8];
            int bc = w * 64 + i * 16 + lrow;
            bh[i] = *(short8v*)&Bh[bc * LDK + kblk * 8];
        }
#pragma unroll
        for (int i = 0; i < 4; ++i)
#pragma unroll
            for (int j = 0; j < 4; ++j) {
                acc[i][j] = __builtin_amdgcn_mfma_f32_16x16x32_bf16(ah[i], bh[j], acc[i][j], 0, 0, 0);
                acc[i][j] = __builtin_amdgcn_mfma_f32_16x16x32_bf16(al[i], bh[j], acc[i][j], 0, 0, 0);
            }
        __syncthreads();
    }

    // C/D layout: col=lane&15, row=(lane>>4)*4+reg  [m89-verified]
    int lc = lane & 15, lq = lane >> 4;

    float ats[4], atd[4];
#pragma unroll
    for (int j = 0; j < 4; ++j) {
        int col = w * 64 + j * 16 + lc;
        ats[j] = att_s[col];
        atd[j] = att_d[col];
    }

#pragma unroll
    for (int i = 0; i < 4; ++i) {
#pragma unroll
        for (int r = 0; r < 4; ++r) {
            int grow = brow + i * 16 + lq * 4 + r;
            if (grow < N) {
#pragma unroll
                for (int j = 0; j < 4; ++j) {
                    int col = w * 64 + j * 16 + lc;
                    hb[(size_t)grow * NFEAT + col] =
                        __hip_bfloat16_raw(__float2bfloat16(acc[i][j][r])).x;
                }
            }
            // a_s/a_d partials: head = w*2 + (j>>1); reduce over 16 lanes (lc)
            float ps0 = acc[i][0][r] * ats[0] + acc[i][1][r] * ats[1];
            float ps1 = acc[i][2][r] * ats[2] + acc[i][3][r] * ats[3];
            float pd0 = acc[i][0][r] * atd[0] + acc[i][1][r] * atd[1];
            float pd1 = acc[i][2][r] * atd[2] + acc[i][3][r] * atd[3];
#pragma unroll
            for (int off = 8; off; off >>= 1) {
                ps0 += __shfl_xor(ps0, off, 16);
                ps1 += __shfl_xor(ps1, off, 16);
                pd0 += __shfl_xor(pd0, off, 16);
                pd1 += __shfl_xor(pd1, off, 16);
            }
            if (lc == 0 && grow < N) {
                a_s[grow * NHEADS + w * 2 + 0] = ps0;
                a_s[grow * NHEADS + w * 2 + 1] = ps1;
                a_d[grow * NHEADS + w * 2 + 0] = pd0;
                a_d[grow * NHEADS + w * 2 + 1] = pd1;
            }
        }
    }
}

__global__ void count_kernel(const int* __restrict__ ei, int* __restrict__ counts, int E) {
    int e = blockIdx.x * 256 + threadIdx.x;
    if (e < E) atomicAdd(&counts[ei[E + e]], 1);
}

// --- hierarchical exclusive scan of counts -> offsets (+cursor) ---
__global__ __launch_bounds__(256) void psum_kernel(const int* __restrict__ counts,
                                                   int* __restrict__ bsum, int N) {
    int i = blockIdx.x * 256 + threadIdx.x;
    int v = (i < N) ? counts[i] : 0;
#pragma unroll
    for (int off = 32; off; off >>= 1) v += __shfl_xor(v, off, 64);
    __shared__ int ws[4];
    int lane = threadIdx.x & 63, wid = threadIdx.x >> 6;
    if (lane == 0) ws[wid] = v;
    __syncthreads();
    if (threadIdx.x == 0) bsum[blockIdx.x] = ws[0] + ws[1] + ws[2] + ws[3];
}

__global__ __launch_bounds__(256) void bscan_kernel(const int* __restrict__ bsum,
                                                    int* __restrict__ bpre, int NB) {
    int t = threadIdx.x;
    int v = (t < NB) ? bsum[t] : 0;
    int lane = t & 63, wid = t >> 6;
    int incl = v;
#pragma unroll
    for (int off = 1; off < 64; off <<= 1) {
        int u = __shfl_up(incl, off, 64);
        if (lane >= off) incl += u;
    }
    __shared__ int wt[4];
    if (lane == 63) wt[wid] = incl;
    __syncthreads();
    int wpre = 0;
    for (int ww = 0; ww < wid; ++ww) wpre += wt[ww];
    if (t < NB) bpre[t] = wpre + incl - v;
}

__global__ __launch_bounds__(256) void addback_kernel(const int* __restrict__ counts,
                                                      const int* __restrict__ bpre,
                                                      int* __restrict__ offsets,
                                                      int* __restrict__ cursor, int N) {
    int blk = blockIdx.x, t = threadIdx.x;
    int i = blk * 256 + t;
    int v = (i < N) ? counts[i] : 0;
    int lane = t & 63, wid = t >> 6;
    int incl = v;
#pragma unroll
    for (int off = 1; off < 64; off <<= 1) {
        int u = __shfl_up(incl, off, 64);
        if (lane >= off) incl += u;
    }
    __shared__ int wt[4];
    if (lane == 63) wt[wid] = incl;
    __syncthreads();
    int wpre = 0;
    for (int ww = 0; ww < wid; ++ww) wpre += wt[ww];
    int pre = bpre[blk] + wpre + incl - v;
    if (i < N) { offsets[i] = pre; cursor[i] = pre; }
    if (i == N - 1) offsets[N] = pre + v;
}

// CSR fill fused with edge-weight computation: w[pos][hd] = exp(leaky(a_s+a_d)).
__global__ void fill_kernel(const int* __restrict__ ei, int* __restrict__ cursor,
                            int* __restrict__ csr_src,
                            const float* __restrict__ a_s, const float* __restrict__ a_d,
                            float* __restrict__ wv, int E) {
    int e = blockIdx.x * 256 + threadIdx.x;
    if (e >= E) return;
    int s = ei[e];
    int d = ei[E + e];
    int pos = atomicAdd(&cursor[d], 1);
    csr_src[pos] = s;
    float4 as0 = *(const float4*)(a_s + (size_t)s * NHEADS);
    float4 as1 = *(const float4*)(a_s + (size_t)s * NHEADS + 4);
    float4 ad0 = *(const float4*)(a_d + (size_t)d * NHEADS);
    float4 ad1 = *(const float4*)(a_d + (size_t)d * NHEADS + 4);
    float4 w0, w1;
    w0.x = __expf(leaky02(as0.x + ad0.x));
    w0.y = __expf(leaky02(as0.y + ad0.y));
    w0.z = __expf(leaky02(as0.z + ad0.z));
    w0.w = __expf(leaky02(as0.w + ad0.w));
    w1.x = __expf(leaky02(as1.x + ad1.x));
    w1.y = __expf(leaky02(as1.y + ad1.y));
    w1.z = __expf(leaky02(as1.z + ad1.z));
    w1.w = __expf(leaky02(as1.w + ad1.w));
    *(float4*)(wv + (size_t)pos * NHEADS) = w0;
    *(float4*)(wv + (size_t)pos * NHEADS + 4) = w1;
}

// Wave-per-node aggregate: 4 nodes/block. Wave = 2 edge-groups x 32 lanes;
// lane handles 8 feats (head hd8 = (lane&31)>>2). Single pass: num += w*h,
// den += w; halves combined via shfl_xor(32); out = num/den (+bias, ELU).
__global__ __launch_bounds__(256) void aggregate_kernel(
    const unsigned short* __restrict__ hb, const float* __restrict__ a_s,
    const float* __restrict__ a_d, const int* __restrict__ offsets,
    const int* __restrict__ csr_src, const float* __restrict__ wv,
    const float* __restrict__ b0, float* __restrict__ out, int N) {
    int wid = threadIdx.x >> 6;
    int lane = threadIdx.x & 63;
    int n = blockIdx.x * 4 + wid;
    if (n >= N) return;
    int eg = lane >> 5;     // 0/1: even/odd edges
    int f8 = lane & 31;     // feature octet [f8*8, f8*8+8)
    int hd8 = f8 >> 2;      // head of this octet

    int start = offsets[n];
    int deg = offsets[n + 1] - start;

    // self-loop weight (virtual edge at i == deg)
    float sw = __expf(leaky02(a_s[(size_t)n * NHEADS + hd8] + a_d[(size_t)n * NHEADS + hd8]));

    float acc[8] = {};
    float den = 0.f;
    for (int i = eg; i < deg + 1; i += 2) {
        int s; float wq;
        if (i < deg) {
            int p = start + i;
            s = csr_src[p];
            wq = wv[(size_t)p * NHEADS + hd8];
        } else {
            s = n;
            wq = sw;
        }
        short8v hv = *(const short8v*)(hb + (size_t)s * NFEAT + f8 * 8);
#pragma unroll
        for (int k = 0; k < 8; ++k)
            acc[k] += wq * bf2f((unsigned short)hv[k]);
        den += wq;
    }
#pragma unroll
    for (int k = 0; k < 8; ++k) acc[k] += __shfl_xor(acc[k], 32, 64);
    den += __shfl_xor(den, 32, 64);
    float inv = 1.f / (den + 1e-16f);

    if (eg == 0) {
        float o[8];
#pragma unroll
        for (int k = 0; k < 8; ++k) {
            float t = acc[k] * inv + b0[f8 * 8 + k];
            o[k] = t > 0.f ? t : (__expf(t) - 1.f);
        }
        float4 v0 = make_float4(o[0], o[1], o[2], o[3]);
        float4 v1 = make_float4(o[4], o[5], o[6], o[7]);
        *(float4*)(out + (size_t)n * NFEAT + f8 * 8) = v0;
        *(float4*)(out + (size_t)n * NFEAT + f8 * 8 + 4) = v1;
    }
}

extern "C" void kernel_launch(void* const* d_in, const int* in_sizes, int n_in,
                              void* d_out, int out_size, void* d_ws, size_t ws_size,
                              hipStream_t stream) {
    const float* x     = (const float*)d_in[0];
    const int*   ei    = (const int*)d_in[1];
    const float* W0    = (const float*)d_in[2];
    const float* att_s = (const float*)d_in[3];
    const float* att_d = (const float*)d_in[4];
    const float* b0    = (const float*)d_in[5];
    float* out = (float*)d_out;

    int N = in_sizes[0] / NFEAT;  // 50000
    int E = in_sizes[1] / 2;      // 800000
    int NB = (N + 255) / 256;     // scan blocks

    char* base = (char*)d_ws;
    size_t off = 0;
    auto nxt = [&](size_t bytes) -> void* {
        void* p = base + off;
        off = (off + bytes + 255) & ~(size_t)255;
        return p;
    };
    unsigned short* hb = (unsigned short*)nxt(sizeof(unsigned short) * (size_t)N * NFEAT);
    unsigned short* Wb = (unsigned short*)nxt(sizeof(unsigned short) * 256 * 256);
    float* a_s     = (float*)nxt(sizeof(float) * (size_t)N * NHEADS);
    float* a_d     = (float*)nxt(sizeof(float) * (size_t)N * NHEADS);
    float* wv      = (float*)nxt(sizeof(float) * (size_t)E * NHEADS);
    int*   counts  = (int*)nxt(sizeof(int) * N);
    int*   offsets = (int*)nxt(sizeof(int) * (N + 1));
    int*   cursor  = (int*)nxt(sizeof(int) * N);
    int*   csr     = (int*)nxt(sizeof(int) * E);
    int*   bsum    = (int*)nxt(sizeof(int) * NB);
    int*   bpre    = (int*)nxt(sizeof(int) * NB);

    hipMemsetAsync(counts, 0, sizeof(int) * N, stream);

    wsplit_kernel<<<256, 256, 0, stream>>>(W0, Wb);
    gemm_h<<<dim3((N + 63) / 64), 256, 0, stream>>>(x, Wb, att_s, att_d, hb, a_s, a_d, N);
    count_kernel<<<(E + 255) / 256, 256, 0, stream>>>(ei, counts, E);
    psum_kernel<<<NB, 256, 0, stream>>>(counts, bsum, N);
    bscan_kernel<<<1, 256, 0, stream>>>(bsum, bpre, NB);
    addback_kernel<<<NB, 256, 0, stream>>>(counts, bpre, offsets, cursor, N);
    fill_kernel<<<(E + 255) / 256, 256, 0, stream>>>(ei, cursor, csr, a_s, a_d, wv, E);
    aggregate_kernel<<<(N + 3) / 4, 256, 0, stream>>>(hb, a_s, a_d, offsets, csr, wv, b0, out, N);
}